// Round 5
// baseline (770.816 us; speedup 1.0000x reference)
//
#include <hip/hip_runtime.h>
#include <math.h>

// Depth collapses to d=0 (x[:, :, 0:1] slicing): conv1d -> w[3]*xi+b,
// scan at d=0 -> hs[0]=BX[0] (A_log unused), y = xi*(delta*sum(B*C)+D).
//
// Round-5: same structure as round-4 (3 dispatches: cnt-memset, fused l0,
// fused l1), with the hs staging index bug fixed (linear write was adding
// c*84 twice -> wrong conv inputs + LDS overflow).
//  - conv blocks (48 rows x 6 og x 8 cs) write acc partials; per-row
//    atomicAdd (agent scope) elects last block as the row's ssm owner.
//  - conv weights fp32 staged to LDS transposed [c][k][o] (coalesced
//    global float4 reads, conflict-free LDS reads).
//  - tail = verified wave-local ssm body, 6 px/wave; out_proj batched
//    over 6 px per opw row-chunk load.
#define NB   2
#define CM   96      // D_MODEL
#define CI   192     // D_INNER
#define CO   384     // 2*D_INNER
#define HP   24
#define WP   24
#define PX   576
#define DTR  6
#define NDBC 38
#define CSPLIT 8
#define CCH  12      // input channels per conv chunk (96/CSPLIT)
#define IPW_L (CO*CM*9)   // floats per layer of in_proj

__device__ __forceinline__ float siluf(float x){ return x / (1.f + expf(-x)); }
__device__ __forceinline__ float softplusf(float x){ return x > 20.f ? x : log1pf(expf(x)); }

__global__ __launch_bounds__(256) void fused_k(
    const float* __restrict__ x, long nStr, long cStr,   // layer input (also residual)
    const float* __restrict__ nw,
    const float* __restrict__ ipw,      // layer base: [o][c][9] fp32
    const float* __restrict__ c1w, const float* __restrict__ c1b,
    const float* __restrict__ xpw, const float* __restrict__ dtw,
    const float* __restrict__ dtb, const float* __restrict__ Dp,
    const float* __restrict__ opw,      // layer base: [m][c] row-major
    float* __restrict__ acc,
    unsigned* __restrict__ cnt,         // 48 per-row counters, pre-zeroed
    float* __restrict__ dst)
{
    __shared__ float wlds[CCH*9*64];    // 27648 B; tail reuses as gl[4][6][CI]
    __shared__ float hs[CCH][3][28];    // 28-wide rows: every (c,j) base 16B-aligned
    __shared__ float scl[CCH][3];
    __shared__ unsigned wflag;

    int bx = blockIdx.x, og = blockIdx.y, cs = blockIdx.z;
    int n  = bx / HP, hh = bx % HP;
    int tid = threadIdx.x;
    int c0 = cs*CCH;

    // ---- stage conv weights -> LDS transposed [c][k][ol]
    {
        const float* wsrc = ipw + (long)og*64*(CM*9) + cs*(CCH*9);
        #pragma unroll
        for (int it = 0; it < 7; it++){
            int li4 = it*256 + tid;
            if (li4 < 64*27){
                int ol2 = li4 / 27, q = li4 % 27;
                float4 v = *(const float4*)(wsrc + (long)ol2*(CM*9) + q*4);
                int t0 = q*4;
                wlds[((t0+0)/9)*576 + ((t0+0)%9)*64 + ol2] = v.x;
                wlds[((t0+1)/9)*576 + ((t0+1)%9)*64 + ol2] = v.y;
                wlds[((t0+2)/9)*576 + ((t0+2)%9)*64 + ol2] = v.z;
                wlds[((t0+3)/9)*576 + ((t0+3)%9)*64 + ol2] = v.w;
            }
        }
    }

    if (tid < CCH*3){
        int c = tid/3, j = tid%3;
        int row = hh + j - 1;
        float s = 0.f;
        if (row >= 0 && row < HP){
            const float4* xp4 = (const float4*)(x + (long)n*nStr + (long)(c0+c)*cStr + row*WP);
            #pragma unroll
            for (int w4 = 0; w4 < WP/4; w4++){
                float4 v = xp4[w4];
                s += v.x*v.x + v.y*v.y + v.z*v.z + v.w*v.w;
            }
            s = rsqrtf(s*(1.0f/WP) + 1e-5f) * nw[c0+c];
        }
        scl[c][j] = s;
    }
    __syncthreads();

    for (int idx = tid; idx < CCH*3*28; idx += 256){
        int c = idx/84; int rem = idx%84; int j = rem/28; int wc = rem%28;
        int row = hh + j - 1;
        float v = 0.f;
        if (row >= 0 && row < HP && wc >= 1 && wc <= WP)
            v = x[(long)n*nStr + (long)(c0+c)*cStr + row*WP + (wc-1)] * scl[c][j];
        ((float*)hs)[idx] = v;   // idx == c*84 + j*28 + wc
    }
    __syncthreads();

    int ol = tid & 63;
    int o  = og*64 + ol;
    int x0 = (tid >> 6) * 6;           // even -> 8B-aligned float2 loads
    float a0[6] = {0,0,0,0,0,0};

    for (int c = 0; c < CCH; c++){
        const float* wl = wlds + c*576 + ol;
        float w0 = wl[0],   w1 = wl[64],  w2 = wl[128];
        float w3 = wl[192], w4 = wl[256], w5 = wl[320];
        float w6 = wl[384], w7 = wl[448], w8 = wl[512];
        float r0v[8], r1v[8], r2v[8];
        #pragma unroll
        for (int i = 0; i < 4; i++){
            float2 p0 = *(const float2*)(&hs[c][0][x0] + 2*i);
            float2 p1 = *(const float2*)(&hs[c][1][x0] + 2*i);
            float2 p2 = *(const float2*)(&hs[c][2][x0] + 2*i);
            r0v[2*i] = p0.x; r0v[2*i+1] = p0.y;
            r1v[2*i] = p1.x; r1v[2*i+1] = p1.y;
            r2v[2*i] = p2.x; r2v[2*i+1] = p2.y;
        }
        #pragma unroll
        for (int p = 0; p < 6; p++){
            a0[p] += w0*r0v[p] + w1*r0v[p+1] + w2*r0v[p+2]
                   + w3*r1v[p] + w4*r1v[p+1] + w5*r1v[p+2]
                   + w6*r2v[p] + w7*r2v[p+1] + w8*r2v[p+2];
        }
    }

    float* ap = acc + ((long)(cs*NB + n)*PX + hh*WP + x0)*CO + o;
    #pragma unroll
    for (int p = 0; p < 6; p++) ap[p*CO] = a0[p];

    // ---- completion: last block of this row owns the ssm tail (no spin)
    __threadfence();
    __syncthreads();
    if (tid == 0){
        unsigned old = __hip_atomic_fetch_add(&cnt[n*HP + hh], 1u,
                           __ATOMIC_ACQ_REL, __HIP_MEMORY_SCOPE_AGENT);
        wflag = (old == (unsigned)(6*CSPLIT - 1)) ? 1u : 0u;
    }
    __syncthreads();
    if (!wflag) return;
    __threadfence();          // invalidate L1 before reading other blocks' acc
    __syncthreads();          // wlds conv reads done -> safe to reuse as gl

    // ---- ssm tail: wave wv handles pixels hh*24 + wv*6 .. +6
    int wv = tid >> 6, lane = tid & 63;
    float* gl = wlds + wv*(6*CI);

    for (int i = 0; i < 6; i++){
        int px = hh*WP + wv*6 + i;
        float xi[3], sz[3];
        #pragma unroll
        for (int t = 0; t < 3; t++){
            int c = lane + 64*t;
            float xr = 0.f, zr = 0.f;
            #pragma unroll
            for (int q = 0; q < CSPLIT; q++){
                const float* ap2 = acc + ((long)(q*NB + n)*PX + px)*CO;
                xr += ap2[c]; zr += ap2[CI + c];
            }
            xi[t] = siluf(xr*c1w[c*4 + 3] + c1b[c]);
            sz[t] = siluf(zr);
        }

        float dbc[NDBC];
        #pragma unroll
        for (int j = 0; j < NDBC; j++){
            float s = 0.f;
            #pragma unroll
            for (int t = 0; t < 3; t++) s += xi[t]*xpw[j*CI + lane + 64*t];
            dbc[j] = s;
        }
        #pragma unroll
        for (int step = 1; step < 64; step <<= 1){
            #pragma unroll
            for (int j = 0; j < NDBC; j++) dbc[j] += __shfl_xor(dbc[j], step, 64);
        }
        float BC = 0.f;
        #pragma unroll
        for (int si = 0; si < 16; si++) BC += dbc[6+si]*dbc[22+si];

        #pragma unroll
        for (int t = 0; t < 3; t++){
            int c = lane + 64*t;
            float dl = dtb[c];
            #pragma unroll
            for (int r = 0; r < DTR; r++) dl += dbc[r]*dtw[c*DTR + r];
            dl = softplusf(dl);
            gl[i*CI + c] = xi[t]*(dl*BC + Dp[c])*sz[t];
        }
    }
    // wave-local LDS RAW: drain ds_writes before broadcast reads
    asm volatile("s_waitcnt lgkmcnt(0)" ::: "memory");

    // ---- out_proj + residual, batched over the 6 pixels per opw-row chunk
    int m0 = lane, m1 = 64 + lane;
    bool hasm1 = (m1 < CM);
    float s0[6] = {0,0,0,0,0,0}, s1[6] = {0,0,0,0,0,0};
    const float* w0p = opw + (long)m0*CI;
    const float* w1p = opw + (long)m1*CI;
    for (int c4 = 0; c4 < CI; c4 += 4){
        float4 g0 = *(const float4*)(gl + 0*CI + c4);
        float4 g1 = *(const float4*)(gl + 1*CI + c4);
        float4 g2 = *(const float4*)(gl + 2*CI + c4);
        float4 g3 = *(const float4*)(gl + 3*CI + c4);
        float4 g4 = *(const float4*)(gl + 4*CI + c4);
        float4 g5 = *(const float4*)(gl + 5*CI + c4);
        float4 wv0 = *(const float4*)(w0p + c4);
        s0[0] += g0.x*wv0.x + g0.y*wv0.y + g0.z*wv0.z + g0.w*wv0.w;
        s0[1] += g1.x*wv0.x + g1.y*wv0.y + g1.z*wv0.z + g1.w*wv0.w;
        s0[2] += g2.x*wv0.x + g2.y*wv0.y + g2.z*wv0.z + g2.w*wv0.w;
        s0[3] += g3.x*wv0.x + g3.y*wv0.y + g3.z*wv0.z + g3.w*wv0.w;
        s0[4] += g4.x*wv0.x + g4.y*wv0.y + g4.z*wv0.z + g4.w*wv0.w;
        s0[5] += g5.x*wv0.x + g5.y*wv0.y + g5.z*wv0.z + g5.w*wv0.w;
        if (hasm1){
            float4 wv1 = *(const float4*)(w1p + c4);
            s1[0] += g0.x*wv1.x + g0.y*wv1.y + g0.z*wv1.z + g0.w*wv1.w;
            s1[1] += g1.x*wv1.x + g1.y*wv1.y + g1.z*wv1.z + g1.w*wv1.w;
            s1[2] += g2.x*wv1.x + g2.y*wv1.y + g2.z*wv1.z + g2.w*wv1.w;
            s1[3] += g3.x*wv1.x + g3.y*wv1.y + g3.z*wv1.z + g3.w*wv1.w;
            s1[4] += g4.x*wv1.x + g4.y*wv1.y + g4.z*wv1.z + g4.w*wv1.w;
            s1[5] += g5.x*wv1.x + g5.y*wv1.y + g5.z*wv1.z + g5.w*wv1.w;
        }
    }
    #pragma unroll
    for (int i = 0; i < 6; i++){
        int px = hh*WP + wv*6 + i;
        dst[(n*CM + m0)*PX + px] = s0[i] + x[(long)n*nStr + (long)m0*cStr + px];
        if (hasm1)
            dst[(n*CM + m1)*PX + px] = s1[i] + x[(long)n*nStr + (long)m1*cStr + px];
    }
}

extern "C" void kernel_launch(void* const* d_in, const int* in_sizes, int n_in,
                              void* d_out, int out_size, void* d_ws, size_t ws_size,
                              hipStream_t stream) {
    const float* x_in = (const float*)d_in[0];   // (2,96,8,24,24)
    const float* ipw  = (const float*)d_in[1];   // (2,384,96,1,3,3)
    const float* c1w  = (const float*)d_in[2];   // (2,192,1,4,1,1)
    const float* c1b  = (const float*)d_in[3];   // (2,192)
    const float* xpw  = (const float*)d_in[4];   // (2,38,192)
    const float* dtw  = (const float*)d_in[5];   // (2,192,6)
    const float* dtb  = (const float*)d_in[6];   // (2,192)
    // d_in[7] = A_log: unused at depth 0 (multiplies h[-1]=0)
    const float* Dp   = (const float*)d_in[8];   // (2,192)
    const float* opw  = (const float*)d_in[9];   // (2,96,192)
    const float* nw   = (const float*)d_in[10];  // (2,1,96,1,1,1)

    char* ws = (char*)d_ws;
    float* acc = (float*)ws;                                // 8*2*576*384 f = 14155776 B
    float* x1  = acc + (long)CSPLIT*NB*PX*CO;               // 110592 f
    unsigned* cnt = (unsigned*)(x1 + (long)NB*CM*PX);       // 96 counters

    // counters must be zero every launch (ws re-poisoned between iters)
    hipMemsetAsync(cnt, 0, 2*NB*HP*sizeof(unsigned), stream);

    // ---- layer 0 (input: depth-0 slice of x, strides of (2,96,8,24,24))
    fused_k<<<dim3(NB*HP, 6, CSPLIT), 256, 0, stream>>>(
        x_in, 96L*8*PX, 8L*PX, nw, ipw,
        c1w, c1b, xpw, dtw, dtb, Dp, opw,
        acc, cnt, x1);

    // ---- layer 1 (input x1 packed (2,96,24,24); writes final output)
    fused_k<<<dim3(NB*HP, 6, CSPLIT), 256, 0, stream>>>(
        x1, 96L*PX, (long)PX, nw + CM, ipw + IPW_L,
        c1w + CI*4, c1b + CI, xpw + NDBC*CI, dtw + CI*DTR, dtb + CI, Dp + CI,
        opw + CM*CI,
        acc, cnt + NB*HP, (float*)d_out);
}

// Round 6
// 154.465 us; speedup vs baseline: 4.9902x; 4.9902x over previous
//
#include <hip/hip_runtime.h>
#include <math.h>

// Depth collapses to d=0 (x[:, :, 0:1] slicing): conv1d -> w[3]*xi+b,
// scan at d=0 -> hs[0]=BX[0] (A_log unused), y = xi*(delta*sum(B*C)+D).
//
// Round-6: round-0's verified 5-dispatch structure (prep, conv0, ssm0,
// conv1, ssm1) with conv og-collapsed 6->2:
//  - each conv block computes 3 o-chunks of 64 (c-loop outermost), so hs
//    staging + rmsnorm scl + barriers amortize 3x, and the hs LDS row
//    reads are shared across the 3 chunks (LDS read traffic / 3).
//  - grid 2304 -> 768 blocks = exactly 3/CU, uniform (kills the 256-block
//    dispatch tail of round-0).
//  - prep_k / ssm_k byte-identical to the 161.98us baseline.
// Round-1/5 lessons baked in: NO intra-kernel cross-block dataflow (agent
// fences = serialized L2 flushes on 8 XCDs), NO spin barriers.
#define NB   2
#define CM   96      // D_MODEL
#define CI   192     // D_INNER
#define CO   384     // 2*D_INNER
#define HP   24
#define WP   24
#define PX   576
#define DTR  6
#define NDBC 38
#define CSPLIT 8
#define CCH  12      // input channels per conv chunk (96/CSPLIT)

__device__ __forceinline__ float siluf(float x){ return x / (1.f + expf(-x)); }
__device__ __forceinline__ float softplusf(float x){ return x > 20.f ? x : log1pf(expf(x)); }
__device__ __forceinline__ unsigned short f2bf(float f){
    unsigned u = __float_as_uint(f);
    return (unsigned short)((u + 0x7fffu + ((u >> 16) & 1u)) >> 16);
}
__device__ __forceinline__ float bflo(unsigned u){ return __uint_as_float(u << 16); }
__device__ __forceinline__ float bfhi(unsigned u){ return __uint_as_float(u & 0xffff0000u); }

// ---- prep: pack in_proj weights to bf16: wQb[l][c][o][k0..7] (ushort8 = uint4)
//            + wRb[l][c][o] (tap 8), and transpose out_proj -> wpT[l][c][m] fp32
#define NW_IN (2*CO*CM*9)      // 663552
#define WQB_L (CM*CO*8)        // ushorts per layer
#define WRB_L (CM*CO)
#define WPT_L (CI*CM)
__global__ void prep_k(const float* __restrict__ ipw, const float* __restrict__ opw,
                       unsigned short* __restrict__ wQb, unsigned short* __restrict__ wRb,
                       float* __restrict__ wpT){
    int idx = blockIdx.x*256 + threadIdx.x;
    if (idx < NW_IN){
        int l = idx / (CO*CM*9);
        int r = idx % (CO*CM*9);
        int o = r / (CM*9);
        int r2 = r % (CM*9);
        int c = r2 / 9;
        int k = r2 % 9;
        unsigned short v = f2bf(ipw[idx]);
        if (k < 8) wQb[(long)l*WQB_L + ((c*CO + o)<<3) + k] = v;
        else       wRb[(long)l*WRB_L + c*CO + o] = v;
    } else {
        int j = idx - NW_IN;
        if (j < 2*CI*CM){
            int l = j / (CI*CM);
            int r = j % (CI*CM);
            int c = r / CM;
            int m = r % CM;
            wpT[l*WPT_L + c*CM + m] = opw[(l*CM + m)*CI + c];
        }
    }
}

// ---- conv: fused rmsnorm + 3x3 conv (pad 1), bf16 weights, fp32 accum.
// grid (NB*HP, 2 og2-halves, CSPLIT c-chunks) = 768 blocks, block 256
// (4 waves x 6-px strips). Each block computes 3 o-chunks of 64 outputs;
// c-loop outermost so hs LDS reads are shared across the 3 chunks.
// acc layout: [cs][n][px][o]
__global__ __launch_bounds__(256) void conv_k(
    const float* __restrict__ x, long nStr, long cStr,
    const float* __restrict__ nw,
    const unsigned short* __restrict__ wQb, const unsigned short* __restrict__ wRb,
    float* __restrict__ acc)
{
    __shared__ float hs[CCH][3][28];   // 28-wide rows: every (c,j) row base 16B-aligned
    __shared__ float scl[CCH][3];
    int bx  = blockIdx.x;
    int og2 = blockIdx.y;              // 0..1 -> outputs og2*192 .. +192
    int cs  = blockIdx.z;
    int n  = bx / HP, hh = bx % HP;
    int tid = threadIdx.x;
    int c0 = cs*CCH;

    if (tid < CCH*3){
        int c = tid/3, j = tid%3;
        int row = hh + j - 1;
        float s = 0.f;
        if (row >= 0 && row < HP){
            const float4* xp4 = (const float4*)(x + (long)n*nStr + (long)(c0+c)*cStr + row*WP);
            #pragma unroll
            for (int w4 = 0; w4 < WP/4; w4++){
                float4 v = xp4[w4];
                s += v.x*v.x + v.y*v.y + v.z*v.z + v.w*v.w;
            }
            s = rsqrtf(s*(1.0f/WP) + 1e-5f) * nw[c0+c];
        }
        scl[c][j] = s;
    }
    __syncthreads();

    for (int idx = tid; idx < CCH*3*28; idx += 256){
        int c = idx/84; int rem = idx%84; int j = rem/28; int wc = rem%28;
        int row = hh + j - 1;
        float v = 0.f;
        if (row >= 0 && row < HP && wc >= 1 && wc <= WP)
            v = x[(long)n*nStr + (long)(c0+c)*cStr + row*WP + (wc-1)] * scl[c][j];
        hs[c][j][wc] = v;
    }
    __syncthreads();

    int ol = tid & 63;
    int obase = og2*192 + ol;          // + oc*64, oc in 0..2
    int x0 = (tid >> 6) * 6;           // even -> 8B-aligned float2 loads
    float a0[3][6] = {{0,0,0,0,0,0},{0,0,0,0,0,0},{0,0,0,0,0,0}};
    const uint4* wq4 = (const uint4*)wQb;

    for (int c = 0; c < CCH; c++){
        int cg = c0 + c;
        float r0v[8], r1v[8], r2v[8];
        #pragma unroll
        for (int i = 0; i < 4; i++){
            float2 p0 = *(const float2*)(&hs[c][0][x0] + 2*i);
            float2 p1 = *(const float2*)(&hs[c][1][x0] + 2*i);
            float2 p2 = *(const float2*)(&hs[c][2][x0] + 2*i);
            r0v[2*i] = p0.x; r0v[2*i+1] = p0.y;
            r1v[2*i] = p1.x; r1v[2*i+1] = p1.y;
            r2v[2*i] = p2.x; r2v[2*i+1] = p2.y;
        }
        #pragma unroll
        for (int oc = 0; oc < 3; oc++){
            int o = obase + oc*64;
            uint4 wv = wq4[cg*CO + o];
            float w0 = bflo(wv.x), w1 = bfhi(wv.x);
            float w2 = bflo(wv.y), w3 = bfhi(wv.y);
            float w4 = bflo(wv.z), w5 = bfhi(wv.z);
            float w6 = bflo(wv.w), w7 = bfhi(wv.w);
            float w8 = bflo((unsigned)wRb[cg*CO + o]);
            #pragma unroll
            for (int p = 0; p < 6; p++){
                a0[oc][p] += w0*r0v[p] + w1*r0v[p+1] + w2*r0v[p+2]
                           + w3*r1v[p] + w4*r1v[p+1] + w5*r1v[p+2]
                           + w6*r2v[p] + w7*r2v[p+1] + w8*r2v[p+2];
            }
        }
    }

    #pragma unroll
    for (int oc = 0; oc < 3; oc++){
        float* ap = acc + ((long)(cs*NB + n)*PX + hh*WP + x0)*CO + obase + oc*64;
        #pragma unroll
        for (int p = 0; p < 6; p++) ap[p*CO] = a0[oc][p];
    }
}

// ---- ssm: sum partials -> conv1d tap + SiLU gates -> x_proj/dt/BC -> gate ->
//               out_proj + residual. block 256 = 4 waves = 4 pixels; grid NB*PX/4.
__global__ __launch_bounds__(256) void ssmproj_k(
    const float* __restrict__ acc,
    const float* __restrict__ c1w, const float* __restrict__ c1b,
    const float* __restrict__ xpw, const float* __restrict__ dtw,
    const float* __restrict__ dtb, const float* __restrict__ Dp,
    const float* __restrict__ wpT,
    const float* __restrict__ xres, long nStrR, long cStrR,
    float* __restrict__ dst)
{
    __shared__ float gl[4][CI];
    int wave = threadIdx.x >> 6, lane = threadIdx.x & 63;
    int p0 = blockIdx.x*4;
    int p  = p0 + wave;
    int n  = p / PX, px = p % PX;

    float xi[3], sz[3];
    #pragma unroll
    for (int t = 0; t < 3; t++){
        int c = lane + 64*t;
        float xr = 0.f, zr = 0.f;
        #pragma unroll
        for (int q = 0; q < CSPLIT; q++){
            const float* ap = acc + ((long)(q*NB + n)*PX + px)*CO;
            xr += ap[c]; zr += ap[CI + c];
        }
        xi[t] = siluf(xr*c1w[c*4 + 3] + c1b[c]);
        sz[t] = siluf(zr);
    }

    float dbc[NDBC];
    #pragma unroll
    for (int j = 0; j < NDBC; j++){
        float s = 0.f;
        #pragma unroll
        for (int t = 0; t < 3; t++) s += xi[t]*xpw[j*CI + lane + 64*t];
        dbc[j] = s;
    }
    #pragma unroll
    for (int step = 1; step < 64; step <<= 1){
        #pragma unroll
        for (int j = 0; j < NDBC; j++) dbc[j] += __shfl_xor(dbc[j], step, 64);
    }
    float BC = 0.f;
    #pragma unroll
    for (int s = 0; s < 16; s++) BC += dbc[6+s]*dbc[22+s];

    #pragma unroll
    for (int t = 0; t < 3; t++){
        int c = lane + 64*t;
        float dl = dtb[c];
        #pragma unroll
        for (int r = 0; r < DTR; r++) dl += dbc[r]*dtw[c*DTR + r];
        dl = softplusf(dl);
        gl[wave][c] = xi[t]*(dl*BC + Dp[c])*sz[t];
    }
    __syncthreads();

    for (int idx = threadIdx.x; idx < 4*CM; idx += 256){
        int pl = idx / CM, m = idx % CM;
        int pp = p0 + pl;
        int nn = pp / PX, ppx = pp % PX;
        const float* g = gl[pl];
        float s0 = 0.f, s1 = 0.f, s2 = 0.f, s3 = 0.f;
        for (int c = 0; c < CI; c += 4){
            s0 += g[c+0]*wpT[(c+0)*CM + m];
            s1 += g[c+1]*wpT[(c+1)*CM + m];
            s2 += g[c+2]*wpT[(c+2)*CM + m];
            s3 += g[c+3]*wpT[(c+3)*CM + m];
        }
        float s = (s0+s1) + (s2+s3);
        s += xres[(long)nn*nStrR + (long)m*cStrR + ppx];
        dst[(nn*CM + m)*PX + ppx] = s;
    }
}

extern "C" void kernel_launch(void* const* d_in, const int* in_sizes, int n_in,
                              void* d_out, int out_size, void* d_ws, size_t ws_size,
                              hipStream_t stream) {
    const float* x_in = (const float*)d_in[0];   // (2,96,8,24,24)
    const float* ipw  = (const float*)d_in[1];   // (2,384,96,1,3,3)
    const float* c1w  = (const float*)d_in[2];   // (2,192,1,4,1,1)
    const float* c1b  = (const float*)d_in[3];   // (2,192)
    const float* xpw  = (const float*)d_in[4];   // (2,38,192)
    const float* dtw  = (const float*)d_in[5];   // (2,192,6)
    const float* dtb  = (const float*)d_in[6];   // (2,192)
    // d_in[7] = A_log: unused at depth 0 (multiplies h[-1]=0)
    const float* Dp   = (const float*)d_in[8];   // (2,192)
    const float* opw  = (const float*)d_in[9];   // (2,96,192)
    const float* nw   = (const float*)d_in[10];  // (2,1,96,1,1,1)

    char* ws = (char*)d_ws;
    unsigned short* wQb = (unsigned short*)ws;              // 2*294912 ush = 1179648 B
    unsigned short* wRb = wQb + 2*WQB_L;                    // 2*36864 ush  = 147456 B
    float* wpT = (float*)(wRb + 2*WRB_L);                   // 2*18432 f    = 147456 B
    float* acc = wpT + 2*WPT_L;                             // 8*2*576*384 f = 14155776 B
    float* x1  = acc + (long)CSPLIT*NB*PX*CO;               // 110592 f

    prep_k<<<(NW_IN + 2*CI*CM + 255)/256, 256, 0, stream>>>(ipw, opw, wQb, wRb, wpT);

    // ---- layer 0 (input: depth-0 slice of x, strides of (2,96,8,24,24))
    conv_k<<<dim3(NB*HP, 2, CSPLIT), 256, 0, stream>>>(
        x_in, 96L*8*PX, 8L*PX, nw, wQb, wRb, acc);
    ssmproj_k<<<NB*PX/4, 256, 0, stream>>>(
        acc, c1w, c1b, xpw, dtw, dtb, Dp, wpT,
        x_in, 96L*8*PX, 8L*PX, x1);

    // ---- layer 1 (input x1 packed (2,96,24,24); writes final output)
    conv_k<<<dim3(NB*HP, 2, CSPLIT), 256, 0, stream>>>(
        x1, 96L*PX, (long)PX, nw + CM, wQb + WQB_L, wRb + WRB_L, acc);
    ssmproj_k<<<NB*PX/4, 256, 0, stream>>>(
        acc, c1w + CI*4, c1b + CI, xpw + NDBC*CI, dtw + CI*DTR, dtb + CI, Dp + CI, wpT + WPT_L,
        x1, 96L*PX, (long)PX, (float*)d_out);
}